// Round 13
// baseline (238.301 us; speedup 1.0000x reference)
//
#include <hip/hip_runtime.h>
#include <math.h>

#define NB 2
#define NC 64
#define NN 32768
#define NPTS (NB*NN)   // 65536
#define NWAVES 1056
#define NSLOTS 67584   // 264*256

typedef _Float16 half_t;
typedef _Float16 f16x8 __attribute__((ext_vector_type(8)));
typedef _Float16 f16x4 __attribute__((ext_vector_type(4)));
typedef float f32x4 __attribute__((ext_vector_type(4)));

// ---------------------------------------------------------------------------
// 1) transpose feature (B,C,N) -> fT (B,N,C) fp32 (for k_s2) + f16 xh
__global__ void k_transpose(const float* __restrict__ f, float* __restrict__ fT,
                            half_t* __restrict__ xh) {
    int blk = blockIdx.x;
    int b = blk / (NN/64);
    int n0 = (blk % (NN/64)) * 64;
    __shared__ float tile[64][65];
    int t = threadIdx.x;
    int dn = t & 63, c0 = t >> 6;
    for (int i = 0; i < 16; ++i) {
        int c = c0 + i*4;
        tile[c][dn] = f[((size_t)(b*NC + c))*NN + n0 + dn];
    }
    __syncthreads();
    int o = t & 63, d0 = t >> 6;
    for (int i = 0; i < 16; ++i) {
        int dn2 = d0 + i*4;
        size_t idx = ((size_t)(b*NN + n0 + dn2))*64 + o;
        float v = tile[o][dn2];
        fT[idx] = v;
        xh[idx] = (half_t)v;
    }
}

// ---------------------------------------------------------------------------
// 2) per-point top-2: 16 lanes per point (4 channel-quarters x 4 neighbor-
//    quarters), fp64 dot with identical summation order (bit-exact sims).
__global__ __launch_bounds__(256, 4) void k_s2(const float* __restrict__ fT,
                                               const int* __restrict__ knn,
                                               int* __restrict__ s2buf) {
    int t = threadIdx.x;
    int gp = blockIdx.x * 16 + (t >> 4);
    int l16 = t & 15;
    int q4 = l16 & 3;       // channel quarter
    int h4 = l16 >> 2;      // neighbor quarter (4 neighbors)
    int b = gp >> 15;
    const float4* cen4 = (const float4*)(fT + (size_t)gp*64 + q4*16);
    float4 c0 = cen4[0], c1 = cen4[1], c2 = cen4[2], c3 = cen4[3];
    float own[4];
    #pragma unroll
    for (int kk = 0; kk < 4; ++kk) {
        int idx = knn[(gp << 4) + h4*4 + kk];
        const float4* nb = (const float4*)(fT + ((size_t)(b*NN + idx))*64 + q4*16);
        float4 n0 = nb[0], n1 = nb[1], n2 = nb[2], n3 = nb[3];
        double a = 0.0;
        a += (double)c0.x*(double)n0.x + (double)c0.y*(double)n0.y
           + (double)c0.z*(double)n0.z + (double)c0.w*(double)n0.w;
        a += (double)c1.x*(double)n1.x + (double)c1.y*(double)n1.y
           + (double)c1.z*(double)n1.z + (double)c1.w*(double)n1.w;
        a += (double)c2.x*(double)n2.x + (double)c2.y*(double)n2.y
           + (double)c2.z*(double)n2.z + (double)c2.w*(double)n2.w;
        a += (double)c3.x*(double)n3.x + (double)c3.y*(double)n3.y
           + (double)c3.z*(double)n3.z + (double)c3.w*(double)n3.w;
        a += __shfl_xor(a, 1, 64);
        a += __shfl_xor(a, 2, 64);
        own[kk] = (float)a;
    }
    int base16 = t & 48;
    float sims[16];
    #pragma unroll
    for (int j = 0; j < 16; ++j)
        sims[j] = __shfl(own[j & 3], base16 + ((j >> 2) << 2), 64);
    float m = sims[0];
    #pragma unroll
    for (int k = 1; k < 16; ++k) m = fmaxf(m, sims[k]);
    float e[16]; float Z = 0.f;
    #pragma unroll
    for (int k = 0; k < 16; ++k) { e[k] = expf(sims[k]-m); Z += e[k]; }
    float b1 = -1.f, b2 = -1.f; int i1 = -1, i2 = -1;
    #pragma unroll
    for (int k = 0; k < 16; ++k) {
        float a = e[k]/Z;
        if (a > b1)      { b2 = b1; i2 = i1; b1 = a; i1 = k; }
        else if (a > b2) { b2 = a; i2 = k; }
    }
    if (l16 == 0) s2buf[gp] = i2;
}

// ---------------------------------------------------------------------------
// bucketing without global atomics
__global__ void k_hist2(const int* __restrict__ s2buf, int* __restrict__ bh) {
    __shared__ int hst[32];
    int t = threadIdx.x, blk = blockIdx.x;
    if (t < 32) hst[t] = 0;
    __syncthreads();
    int p = blk*256 + t;
    int bucket = (p >> 15)*16 + s2buf[p];
    atomicAdd(&hst[bucket], 1);
    __syncthreads();
    if (t < 32) bh[t*256 + blk] = hst[t];
}

// single block: walk table + totals -> wave-aligned starts -> offsets + padding
__global__ void k_prefix(const int* __restrict__ s2buf, const int* __restrict__ bh,
                         int* __restrict__ blockoff, int* __restrict__ wavebucket,
                         int* __restrict__ slotlist, int* __restrict__ walkrows,
                         int* __restrict__ cnt) {
    __shared__ int tot[32], wst[32], offsh;
    __shared__ int T[16];
    int t = threadIdx.x;
    if (t == 0) *cnt = 0;
    if (t < 16) T[t] = s2buf[t];
    if (t < 32) {
        int s = 0;
        for (int b = 0; b < 256; ++b) s += bh[t*256 + b];
        tot[t] = s;
    }
    __syncthreads();
    if (t < 16) {
        int w = t;
        walkrows[t*16 + 0] = w;
        for (int s = 1; s < 16; ++s) { w = T[w]; walkrows[t*16 + s] = w; }
    }
    if (t == 0) {
        int off = 0;
        for (int i = 0; i < 32; ++i) {
            wst[i] = off;
            off += ((tot[i] + 63) >> 6) << 6;
        }
        offsh = off;
    }
    __syncthreads();
    if (t < 32) {
        int run = wst[t];
        for (int b = 0; b < 256; ++b) {
            blockoff[t*256 + b] = run;
            run += bh[t*256 + b];
        }
        int w0 = wst[t] >> 6, nw = (tot[t] + 63) >> 6;
        for (int w = 0; w < nw; ++w) wavebucket[w0 + w] = t;
        for (int s = wst[t] + tot[t]; s < wst[t] + nw*64; ++s) slotlist[s] = -1;
    }
    __syncthreads();
    int off = offsh;
    for (int w = (off >> 6) + t; w < NWAVES; w += 256) wavebucket[w] = -1;
    for (int s = off + t; s < NSLOTS; s += 256) slotlist[s] = -1;
}

__global__ void k_scatter2(const int* __restrict__ s2buf,
                           const int* __restrict__ blockoff,
                           int* __restrict__ slotlist) {
    __shared__ int hst[32], base[32];
    int t = threadIdx.x, blk = blockIdx.x;
    if (t < 32) { hst[t] = 0; base[t] = blockoff[t*256 + blk]; }
    __syncthreads();
    int p = blk*256 + t;
    int bucket = (p >> 15)*16 + s2buf[p];
    int r = atomicAdd(&hst[bucket], 1);
    slotlist[base[bucket] + r] = p;
}

// ---------------------------------------------------------------------------
// 4) per (b, sv): window QKV -> f16 MFMA tables + softmax stats (+ weight cast)
//    window rows read from the f16 residual stream xh.
__global__ __launch_bounds__(256) void k_precomp(
        const half_t* __restrict__ xh,
        const float* __restrict__ Wq, const float* __restrict__ bq,
        const float* __restrict__ Wk, const float* __restrict__ bk,
        const float* __restrict__ Wv, const float* __restrict__ bv,
        const int* __restrict__ walkrows,
        half_t* __restrict__ Pq16, half_t* __restrict__ Pk16,
        half_t* __restrict__ PvT16, float* __restrict__ Pstat,
        half_t* __restrict__ wh) {
    int blk = blockIdx.x;
    int b = blk >> 4, sv = blk & 15;
    size_t bsv16 = (size_t)(b*16 + sv) * 1024;
    int bs48 = (b*16 + sv)*48;
    __shared__ float win[16][64];
    __shared__ float Wl[64][65];
    __shared__ float qw[16][65], kw[16][65];
    __shared__ float simw[16][17];
    __shared__ int wr[16];
    int t = threadIdx.x;
    #pragma unroll
    for (int j = 0; j < 2; ++j) {
        int idx = j*8192 + blk*256 + t;
        if (idx < 12288) {
            float v = idx < 4096 ? Wq[idx] : (idx < 8192 ? Wk[idx-4096] : Wv[idx-8192]);
            wh[idx] = (half_t)v;
        }
    }
    if (t < 16) wr[t] = walkrows[sv*16 + t];
    __syncthreads();
    #pragma unroll
    for (int i = 0; i < 4; ++i) {
        int idx = t + i*256; int tt = idx >> 6, c = idx & 63;
        win[tt][c] = (float)xh[((size_t)(b*NN + wr[tt]))*64 + c];
    }
    int wv = t >> 6, lane = t & 63;
    for (int m = 0; m < 3; ++m) {
        const float* W  = m == 0 ? Wq : (m == 1 ? Wk : Wv);
        const float* bb = m == 0 ? bq : (m == 1 ? bk : bv);
        __syncthreads();
        #pragma unroll
        for (int i = 0; i < 16; ++i) {
            int idx = t + i*256;
            Wl[idx >> 6][idx & 63] = W[idx];
        }
        __syncthreads();
        float acc[4] = {0.f, 0.f, 0.f, 0.f};
        for (int c = 0; c < 64; ++c) {
            float w_ = Wl[lane][c];
            #pragma unroll
            for (int r = 0; r < 4; ++r) acc[r] = fmaf(w_, win[wv*4 + r][c], acc[r]);
        }
        float bias = bb[lane];
        #pragma unroll
        for (int r = 0; r < 4; ++r) {
            int tt = wv*4 + r;
            float val = acc[r] + bias;
            if (m == 0)      { qw[tt][lane] = val; Pq16[bsv16 + tt*64 + lane] = (half_t)val; }
            else if (m == 1) { kw[tt][lane] = val; Pk16[bsv16 + tt*64 + lane] = (half_t)val; }
            else             {                     PvT16[bsv16 + lane*16 + tt] = (half_t)val; }
        }
    }
    __syncthreads();
    {
        int i = t >> 4, j = t & 15;
        float acc = 0.f;
        for (int o = 0; o < 64; ++o) acc = fmaf(qw[i][o], kw[j][o], acc);
        simw[i][j] = acc;
    }
    __syncthreads();
    if (t < 16) {
        float mx = simw[t][0];
        for (int j = 1; j < 16; ++j) mx = fmaxf(mx, simw[t][j]);
        float z = 0.f;
        for (int j = 0; j < 16; ++j) z += expf(simw[t][j] - mx);
        Pstat[bs48 + t*3 + 0] = mx;
        Pstat[bs48 + t*3 + 1] = z;
        Pstat[bs48 + t*3 + 2] = simw[t][t];
    }
}

// ---------------------------------------------------------------------------
// 5) QKV via f16 MFMA over SLOT-ordered points (input gathered via slotlist).
__global__ __launch_bounds__(256) void k_gemm(
        const half_t* __restrict__ xh, const int* __restrict__ slotlist, int s0,
        const half_t* __restrict__ wh,
        const float* __restrict__ bq, const float* __restrict__ bk,
        const float* __restrict__ bv,
        half_t* __restrict__ qh, half_t* __restrict__ kh, half_t* __restrict__ vh) {
    __shared__ __align__(16) half_t XO[256*72];
    __shared__ __align__(16) half_t WL[192*72];
    int t = threadIdx.x;
    int lane = t & 63, wv = t >> 6;
    size_t go = (size_t)blockIdx.x * 256 * 64;
    {
        int srow = slotlist[s0 + blockIdx.x*256 + t];
        int prow = srow < 0 ? 0 : srow;
        const uint4* src = (const uint4*)(xh + (size_t)prow*64);
        #pragma unroll
        for (int j = 0; j < 8; ++j) *(uint4*)&XO[t*72 + j*8] = src[j];
    }
    #pragma unroll
    for (int j = 0; j < 6; ++j) {
        int idx8 = t + j*256;
        int row = idx8 >> 3, c0 = (idx8 & 7) * 8;
        *(uint4*)&WL[row*72 + c0] = *(const uint4*)(wh + idx8*8);
    }
    __syncthreads();
    int m15 = lane & 15, k0 = (lane >> 4) * 8;
    int ar = wv*64 + m15;
    f16x8 a00 = *(const f16x8*)&XO[(ar    )*72 + k0];
    f16x8 a01 = *(const f16x8*)&XO[(ar    )*72 + k0 + 32];
    f16x8 a10 = *(const f16x8*)&XO[(ar+16)*72 + k0];
    f16x8 a11 = *(const f16x8*)&XO[(ar+16)*72 + k0 + 32];
    f16x8 a20 = *(const f16x8*)&XO[(ar+32)*72 + k0];
    f16x8 a21 = *(const f16x8*)&XO[(ar+32)*72 + k0 + 32];
    f16x8 a30 = *(const f16x8*)&XO[(ar+48)*72 + k0];
    f16x8 a31 = *(const f16x8*)&XO[(ar+48)*72 + k0 + 32];
    __syncthreads();
    #pragma unroll 1
    for (int m = 0; m < 3; ++m) {
        const float* bias = m == 0 ? bq : (m == 1 ? bk : bv);
        half_t* outp      = m == 0 ? qh : (m == 1 ? kh : vh);
        int wb = m*64 + m15;
        f16x8 b00 = *(const f16x8*)&WL[(wb    )*72 + k0];
        f16x8 b01 = *(const f16x8*)&WL[(wb    )*72 + k0 + 32];
        f16x8 b10 = *(const f16x8*)&WL[(wb+16)*72 + k0];
        f16x8 b11 = *(const f16x8*)&WL[(wb+16)*72 + k0 + 32];
        f16x8 b20 = *(const f16x8*)&WL[(wb+32)*72 + k0];
        f16x8 b21 = *(const f16x8*)&WL[(wb+32)*72 + k0 + 32];
        f16x8 b30 = *(const f16x8*)&WL[(wb+48)*72 + k0];
        f16x8 b31 = *(const f16x8*)&WL[(wb+48)*72 + k0 + 32];
        float bs0 = bias[m15], bs1 = bias[16+m15], bs2 = bias[32+m15], bs3 = bias[48+m15];
        f32x4 Z = {0.f, 0.f, 0.f, 0.f};
        f32x4 c00=Z,c01=Z,c02=Z,c03=Z, c10=Z,c11=Z,c12=Z,c13=Z;
        f32x4 c20=Z,c21=Z,c22=Z,c23=Z, c30=Z,c31=Z,c32=Z,c33=Z;
        #define MM(i,j) \
            c##i##j = __builtin_amdgcn_mfma_f32_16x16x32_f16(a##i##0, b##j##0, c##i##j, 0,0,0); \
            c##i##j = __builtin_amdgcn_mfma_f32_16x16x32_f16(a##i##1, b##j##1, c##i##j, 0,0,0);
        MM(0,0) MM(0,1) MM(0,2) MM(0,3)
        MM(1,0) MM(1,1) MM(1,2) MM(1,3)
        MM(2,0) MM(2,1) MM(2,2) MM(2,3)
        MM(3,0) MM(3,1) MM(3,2) MM(3,3)
        #undef MM
        __syncthreads();
        int r0 = wv*64 + ((lane >> 4) << 2);
        #define WR(i,j,bsj) { \
            XO[(r0 + i*16 + 0)*64 + j*16 + m15] = (half_t)(c##i##j[0] + bsj); \
            XO[(r0 + i*16 + 1)*64 + j*16 + m15] = (half_t)(c##i##j[1] + bsj); \
            XO[(r0 + i*16 + 2)*64 + j*16 + m15] = (half_t)(c##i##j[2] + bsj); \
            XO[(r0 + i*16 + 3)*64 + j*16 + m15] = (half_t)(c##i##j[3] + bsj); }
        WR(0,0,bs0) WR(0,1,bs1) WR(0,2,bs2) WR(0,3,bs3)
        WR(1,0,bs0) WR(1,1,bs1) WR(1,2,bs2) WR(1,3,bs3)
        WR(2,0,bs0) WR(2,1,bs1) WR(2,2,bs2) WR(2,3,bs3)
        WR(3,0,bs0) WR(3,1,bs1) WR(3,2,bs2) WR(3,3,bs3)
        #undef WR
        __syncthreads();
        #pragma unroll
        for (int j = 0; j < 8; ++j) {
            int idx = (j*256 + t) * 8;
            *(uint4*)(outp + go + idx) = *(const uint4*)&XO[idx];
        }
    }
}

// ---------------------------------------------------------------------------
// 6) combine v4: MFMA attention, one wave = 16 slots (j-tile = wave id).
__global__ __launch_bounds__(256) void k_comb4(
        const half_t* __restrict__ qh, const half_t* __restrict__ kh,
        const half_t* __restrict__ vh,
        const half_t* __restrict__ Pq16, const half_t* __restrict__ Pk16,
        const half_t* __restrict__ PvT16, const float* __restrict__ Pstat,
        const int* __restrict__ slotlist, const int* __restrict__ wavebucket,
        half_t* __restrict__ xo, int s0) {
    int t = threadIdx.x, j = t >> 6, lane = t & 63;
    int wslot = blockIdx.x*64;
    int gbase = s0 + wslot;
    int bucket = wavebucket[gbase >> 6];
    if (bucket < 0) return;
    int m15 = lane & 15, g4 = lane >> 4;
    int k0h = g4 * 8;
    size_t bsv16 = (size_t)bucket << 10;
    int bs48 = bucket * 48;

    f16x8 pqA0 = *(const f16x8*)&Pq16[bsv16 + m15*64 + k0h];
    f16x8 pqA1 = *(const f16x8*)&Pq16[bsv16 + m15*64 + k0h + 32];
    f16x8 pkA0 = *(const f16x8*)&Pk16[bsv16 + m15*64 + k0h];
    f16x8 pkA1 = *(const f16x8*)&Pk16[bsv16 + m15*64 + k0h + 32];
    f16x4 pvB0 = *(const f16x4*)&PvT16[bsv16 + (0*16 + m15)*16 + g4*4];
    f16x4 pvB1 = *(const f16x4*)&PvT16[bsv16 + (1*16 + m15)*16 + g4*4];
    f16x4 pvB2 = *(const f16x4*)&PvT16[bsv16 + (2*16 + m15)*16 + g4*4];
    f16x4 pvB3 = *(const f16x4*)&PvT16[bsv16 + (3*16 + m15)*16 + g4*4];
    float pm[4], pz[4], dg[4];
    #pragma unroll
    for (int r = 0; r < 4; ++r) {
        pm[r] = Pstat[bs48 + (g4*4+r)*3 + 0];
        pz[r] = Pstat[bs48 + (g4*4+r)*3 + 1];
        dg[r] = Pstat[bs48 + (g4*4+r)*3 + 2];
    }
    int4 pid4 = *(const int4*)&slotlist[gbase + j*16 + g4*4];

    const half_t* kp = kh + (size_t)(wslot + j*16 + m15)*64;
    const half_t* qp = qh + (size_t)(wslot + j*16 + m15)*64;
    f16x8 kB0 = *(const f16x8*)&kp[k0h];
    f16x8 kB1 = *(const f16x8*)&kp[k0h + 32];
    f16x8 qB0 = *(const f16x8*)&qp[k0h];
    f16x8 qB1 = *(const f16x8*)&qp[k0h + 32];
    f32x4 Zz = {0.f,0.f,0.f,0.f};
    f32x4 sp = __builtin_amdgcn_mfma_f32_16x16x32_f16(pqA0, kB0, Zz, 0,0,0);
    sp = __builtin_amdgcn_mfma_f32_16x16x32_f16(pqA1, kB1, sp, 0,0,0);
    f32x4 tp = __builtin_amdgcn_mfma_f32_16x16x32_f16(pkA0, qB0, Zz, 0,0,0);
    tp = __builtin_amdgcn_mfma_f32_16x16x32_f16(pkA1, qB1, tp, 0,0,0);
    float up = 0.f;
    #pragma unroll
    for (int e = 0; e < 8; ++e) {
        up = fmaf((float)qB0[e], (float)kB0[e], up);
        up = fmaf((float)qB1[e], (float)kB1[e], up);
    }
    up += __shfl_xor(up, 16, 64);
    up += __shfl_xor(up, 32, 64);
    float d0, d1, d2, d3;
    {
        float mi, zi;
        mi = fmaxf(pm[0], sp[0]); zi = pz[0]*expf(pm[0]-mi) + expf(sp[0]-mi); d0 = expf(dg[0]-mi)/zi;
        mi = fmaxf(pm[1], sp[1]); zi = pz[1]*expf(pm[1]-mi) + expf(sp[1]-mi); d1 = expf(dg[1]-mi)/zi;
        mi = fmaxf(pm[2], sp[2]); zi = pz[2]*expf(pm[2]-mi) + expf(sp[2]-mi); d2 = expf(dg[2]-mi)/zi;
        mi = fmaxf(pm[3], sp[3]); zi = pz[3]*expf(pm[3]-mi) + expf(sp[3]-mi); d3 = expf(dg[3]-mi)/zi;
    }
    float tmax = fmaxf(fmaxf(tp[0], tp[1]), fmaxf(tp[2], tp[3]));
    tmax = fmaxf(tmax, __shfl_xor(tmax, 16, 64));
    tmax = fmaxf(tmax, __shfl_xor(tmax, 32, 64));
    float mc = fmaxf(tmax, up);
    float ze = expf(tp[0]-mc) + expf(tp[1]-mc) + expf(tp[2]-mc) + expf(tp[3]-mc);
    ze += __shfl_xor(ze, 16, 64);
    ze += __shfl_xor(ze, 32, 64);
    float ec = expf(up - mc);
    float dcen = ec / (ze + ec);
    f16x4 dA; dA[0] = (half_t)d0; dA[1] = (half_t)d1; dA[2] = (half_t)d2; dA[3] = (half_t)d3;

    float dc0 = __shfl(dcen, g4*4 + 0, 64);
    float dc1 = __shfl(dcen, g4*4 + 1, 64);
    float dc2 = __shfl(dcen, g4*4 + 2, 64);
    float dc3 = __shfl(dcen, g4*4 + 3, 64);
    int p0 = pid4.x, p1 = pid4.y, p2 = pid4.z, p3 = pid4.w;
    size_t vb0 = (size_t)(wslot + j*16 + g4*4 + 0)*64;
    size_t vb1 = (size_t)(wslot + j*16 + g4*4 + 1)*64;
    size_t vb2 = (size_t)(wslot + j*16 + g4*4 + 2)*64;
    size_t vb3 = (size_t)(wslot + j*16 + g4*4 + 3)*64;
    #pragma unroll
    for (int jc = 0; jc < 4; ++jc) {
        f16x4 pvB = jc == 0 ? pvB0 : (jc == 1 ? pvB1 : (jc == 2 ? pvB2 : pvB3));
        f32x4 Z2 = {0.f,0.f,0.f,0.f};
        f32x4 acc = __builtin_amdgcn_mfma_f32_16x16x16f16(dA, pvB, Z2, 0,0,0);
        int c = jc*16 + m15;
        float v0 = (float)vh[vb0 + c];
        float v1 = (float)vh[vb1 + c];
        float v2 = (float)vh[vb2 + c];
        float v3 = (float)vh[vb3 + c];
        if (p0 >= 0) xo[(size_t)p0*64 + c] = (half_t)(acc[0] + dc0*v0);
        if (p1 >= 0) xo[(size_t)p1*64 + c] = (half_t)(acc[1] + dc1*v1);
        if (p2 >= 0) xo[(size_t)p2*64 + c] = (half_t)(acc[2] + dc2*v2);
        if (p3 >= 0) xo[(size_t)p3*64 + c] = (half_t)(acc[3] + dc3*v3);
    }
}

// ---------------------------------------------------------------------------
// 7) fused partial sums + final stats (last-block-done, deterministic mv)
__global__ __launch_bounds__(256) void k_reduce2(const half_t* __restrict__ x,
                                                 float* __restrict__ part,
                                                 float* __restrict__ mv,
                                                 int* __restrict__ cnt) {
    __shared__ float ls[4][64], lq[4][64];
    __shared__ int lastf;
    int t = threadIdx.x, q = t >> 6, c = t & 63;
    size_t base = ((size_t)blockIdx.x*128 + q*32) * 64;
    float s = 0.f, sq = 0.f;
    for (int r = 0; r < 32; ++r) {
        float v = (float)x[base + r*64 + c];
        s += v; sq = fmaf(v, v, sq);
    }
    ls[q][c] = s; lq[q][c] = sq;
    __syncthreads();
    if (q == 0) {
        float S = ls[0][c] + ls[1][c] + ls[2][c] + ls[3][c];
        float Q = lq[0][c] + lq[1][c] + lq[2][c] + lq[3][c];
        part[blockIdx.x*64 + c] = S;
        part[512*64 + blockIdx.x*64 + c] = Q;
    }
    __syncthreads();
    if (t == 0) {
        __threadfence();
        int old = atomicAdd(cnt, 1);
        lastf = (old == 511);
    }
    __syncthreads();
    if (!lastf) return;
    __threadfence();
    float s2 = 0.f, sq2 = 0.f;
    for (int r = q*128; r < q*128 + 128; ++r) {
        s2  += part[r*64 + c];
        sq2 += part[512*64 + r*64 + c];
    }
    __syncthreads();
    ls[q][c] = s2; lq[q][c] = sq2;
    __syncthreads();
    if (q == 0) {
        float S = ls[0][c] + ls[1][c] + ls[2][c] + ls[3][c];
        float Q = lq[0][c] + lq[1][c] + lq[2][c] + lq[3][c];
        float mean = S / (float)NPTS;
        float var  = Q / (float)NPTS - mean*mean;
        mv[c] = mean; mv[64 + c] = var;
    }
    if (t == 0) atomicExch(cnt, 0);
}

// ---------------------------------------------------------------------------
// 8) normalize + relu + residual on the f16 stream; write out slice (B,C,N)
__global__ void k_norm(const half_t* __restrict__ x, half_t* __restrict__ xh,
                       const float* __restrict__ mv,
                       const float* __restrict__ gamma, const float* __restrict__ beta,
                       float* __restrict__ out, int l) {
    int blk = blockIdx.x;
    int b = blk / (NN/64);
    int n0 = (blk % (NN/64)) * 64;
    __shared__ float tile[64][65];
    int t = threadIdx.x;
    int c = t & 63, d0 = t >> 6;
    float mean = mv[c], var = mv[64+c];
    float inv = 1.0f / sqrtf(var + 1e-5f);
    float ga = gamma[c], be = beta[c];
    for (int i = 0; i < 16; ++i) {
        int dn = d0 + i*4;
        size_t pi = ((size_t)(b*NN + n0 + dn))*64 + c;
        float xv = (float)x[pi];
        float res = (float)xh[pi];
        float y = res + fmaxf(ga * (xv - mean) * inv + be, 0.f);
        xh[pi] = (half_t)y;
        tile[dn][c] = y;
    }
    __syncthreads();
    int dn2 = t & 63, c0 = t >> 6;
    for (int i = 0; i < 16; ++i) {
        int cc = c0 + i*4;
        out[((size_t)(b*192 + l*64 + cc))*NN + n0 + dn2] = tile[dn2][cc];
    }
}

// ---------------------------------------------------------------------------
extern "C" void kernel_launch(void* const* d_in, const int* in_sizes, int n_in,
                              void* d_out, int out_size, void* d_ws, size_t ws_size,
                              hipStream_t stream) {
    const float* feature = (const float*)d_in[0];
    const int*   knn     = (const int*)d_in[1];
    const float* Wq = (const float*)d_in[2];
    const float* bq = (const float*)d_in[3];
    const float* Wk = (const float*)d_in[4];
    const float* bk = (const float*)d_in[5];
    const float* Wv = (const float*)d_in[6];
    const float* bv = (const float*)d_in[7];
    const float* gamma = (const float*)d_in[8];
    const float* beta  = (const float*)d_in[9];
    float* out = (float*)d_out;

    char* ws = (char*)d_ws;
    float*  fT    = (float*) ws;                        // 16,777,216
    half_t* xh    = (half_t*)(ws + 16777216);           //  8,388,608
    half_t* xo    = (half_t*)(ws + 25165824);           //  8,388,608
    int*    s2buf = (int*)   (ws + 33554432);           //    262,144
    int*    walkrows = (int*)(ws + 33816576);           //      1,024
    half_t* Pq16  = (half_t*)(ws + 33817600);           //     65,536
    half_t* Pk16  = (half_t*)(ws + 33883136);           //     65,536
    half_t* PvT16 = (half_t*)(ws + 33948672);           //     65,536
    float*  Pstat = (float*) (ws + 34014208);           //      6,144
    float*  part  = (float*) (ws + 34020352);           //    262,144
    float*  mv    = (float*) (ws + 34282496);           //        512
    half_t* wh    = (half_t*)(ws + 34283008);           //     24,576
    int*    bh        = (int*)(ws + 34307584);          //     32,768
    int*    blockoff  = (int*)(ws + 34340352);          //     32,768
    int*    wavebucket= (int*)(ws + 34373120);          //      4,224
    int*    slotlist  = (int*)(ws + 34377344);          //    270,336
    int*    cnt       = (int*)(ws + 34647680);          //        256
    size_t  qkv_off = 34647936;

    size_t avail = ws_size > qkv_off ? ws_size - qkv_off : 0;
    size_t chunk = avail / 384;      // 3 x 64 x 2B per slot
    chunk = (chunk / 256) * 256;
    if (chunk > (size_t)NSLOTS) chunk = NSLOTS;
    if (chunk < 256) chunk = 256;
    half_t* qh = (half_t*)(ws + qkv_off);
    half_t* kh = qh + chunk*64;
    half_t* vh = kh + chunk*64;

    k_transpose<<<NB*(NN/64), 256, 0, stream>>>(feature, fT, xh);
    k_s2<<<NPTS/16, 256, 0, stream>>>(fT, knn, s2buf);
    k_hist2<<<NPTS/256, 256, 0, stream>>>(s2buf, bh);
    k_prefix<<<1, 256, 0, stream>>>(s2buf, bh, blockoff, wavebucket, slotlist,
                                    walkrows, cnt);
    k_scatter2<<<NPTS/256, 256, 0, stream>>>(s2buf, blockoff, slotlist);

    for (int l = 0; l < 3; ++l) {
        k_precomp<<<32, 256, 0, stream>>>(xh, Wq + l*4096, bq + l*64,
                                          Wk + l*4096, bk + l*64,
                                          Wv + l*4096, bv + l*64,
                                          walkrows, Pq16, Pk16, PvT16, Pstat, wh);
        for (size_t s0 = 0; s0 < NSLOTS; s0 += chunk) {
            size_t cn = (s0 + chunk <= NSLOTS) ? chunk : (NSLOTS - s0);
            k_gemm<<<(unsigned)(cn/256), 256, 0, stream>>>(xh, slotlist, (int)s0, wh,
                                                           bq + l*64, bk + l*64, bv + l*64,
                                                           qh, kh, vh);
            k_comb4<<<(unsigned)(cn/64), 256, 0, stream>>>(qh, kh, vh,
                                                           Pq16, Pk16, PvT16, Pstat,
                                                           slotlist, wavebucket,
                                                           xo, (int)s0);
        }
        k_reduce2<<<512, 256, 0, stream>>>(xo, part, mv, cnt);
        k_norm<<<NB*(NN/64), 256, 0, stream>>>(xo, xh, mv, gamma + l*64, beta + l*64,
                                               out, l);
    }
}

// Round 14
// 208.049 us; speedup vs baseline: 1.1454x; 1.1454x over previous
//
#include <hip/hip_runtime.h>
#include <math.h>

#define NB 2
#define NC 64
#define NN 32768
#define NPTS (NB*NN)   // 65536
#define NWAVES 1056
#define NSLOTS 67584   // 264*256

typedef _Float16 half_t;
typedef _Float16 f16x8 __attribute__((ext_vector_type(8)));
typedef _Float16 f16x4 __attribute__((ext_vector_type(4)));
typedef float f32x4 __attribute__((ext_vector_type(4)));

// ---------------------------------------------------------------------------
// 1) transpose feature (B,C,N) -> fT (B,N,C) fp32 (for k_s2) + f16 xh
__global__ void k_transpose(const float* __restrict__ f, float* __restrict__ fT,
                            half_t* __restrict__ xh) {
    int blk = blockIdx.x;
    int b = blk / (NN/64);
    int n0 = (blk % (NN/64)) * 64;
    __shared__ float tile[64][65];
    int t = threadIdx.x;
    int dn = t & 63, c0 = t >> 6;
    for (int i = 0; i < 16; ++i) {
        int c = c0 + i*4;
        tile[c][dn] = f[((size_t)(b*NC + c))*NN + n0 + dn];
    }
    __syncthreads();
    int o = t & 63, d0 = t >> 6;
    for (int i = 0; i < 16; ++i) {
        int dn2 = d0 + i*4;
        size_t idx = ((size_t)(b*NN + n0 + dn2))*64 + o;
        float v = tile[o][dn2];
        fT[idx] = v;
        xh[idx] = (half_t)v;
    }
}

// ---------------------------------------------------------------------------
// 2) per-point top-2: 16 lanes per point (4 channel-quarters x 4 neighbor-
//    quarters), fp64 dot with identical summation order (bit-exact sims).
__global__ __launch_bounds__(256, 4) void k_s2(const float* __restrict__ fT,
                                               const int* __restrict__ knn,
                                               int* __restrict__ s2buf) {
    int t = threadIdx.x;
    int gp = blockIdx.x * 16 + (t >> 4);
    int l16 = t & 15;
    int q4 = l16 & 3;       // channel quarter
    int h4 = l16 >> 2;      // neighbor quarter (4 neighbors)
    int b = gp >> 15;
    const float4* cen4 = (const float4*)(fT + (size_t)gp*64 + q4*16);
    float4 c0 = cen4[0], c1 = cen4[1], c2 = cen4[2], c3 = cen4[3];
    float own[4];
    #pragma unroll
    for (int kk = 0; kk < 4; ++kk) {
        int idx = knn[(gp << 4) + h4*4 + kk];
        const float4* nb = (const float4*)(fT + ((size_t)(b*NN + idx))*64 + q4*16);
        float4 n0 = nb[0], n1 = nb[1], n2 = nb[2], n3 = nb[3];
        double a = 0.0;
        a += (double)c0.x*(double)n0.x + (double)c0.y*(double)n0.y
           + (double)c0.z*(double)n0.z + (double)c0.w*(double)n0.w;
        a += (double)c1.x*(double)n1.x + (double)c1.y*(double)n1.y
           + (double)c1.z*(double)n1.z + (double)c1.w*(double)n1.w;
        a += (double)c2.x*(double)n2.x + (double)c2.y*(double)n2.y
           + (double)c2.z*(double)n2.z + (double)c2.w*(double)n2.w;
        a += (double)c3.x*(double)n3.x + (double)c3.y*(double)n3.y
           + (double)c3.z*(double)n3.z + (double)c3.w*(double)n3.w;
        a += __shfl_xor(a, 1, 64);
        a += __shfl_xor(a, 2, 64);
        own[kk] = (float)a;
    }
    int base16 = t & 48;
    float sims[16];
    #pragma unroll
    for (int j = 0; j < 16; ++j)
        sims[j] = __shfl(own[j & 3], base16 + ((j >> 2) << 2), 64);
    float m = sims[0];
    #pragma unroll
    for (int k = 1; k < 16; ++k) m = fmaxf(m, sims[k]);
    float e[16]; float Z = 0.f;
    #pragma unroll
    for (int k = 0; k < 16; ++k) { e[k] = expf(sims[k]-m); Z += e[k]; }
    float b1 = -1.f, b2 = -1.f; int i1 = -1, i2 = -1;
    #pragma unroll
    for (int k = 0; k < 16; ++k) {
        float a = e[k]/Z;
        if (a > b1)      { b2 = b1; i2 = i1; b1 = a; i1 = k; }
        else if (a > b2) { b2 = a; i2 = k; }
    }
    if (l16 == 0) s2buf[gp] = i2;
}

// ---------------------------------------------------------------------------
// bucketing without global atomics
__global__ void k_hist2(const int* __restrict__ s2buf, int* __restrict__ bh) {
    __shared__ int hst[32];
    int t = threadIdx.x, blk = blockIdx.x;
    if (t < 32) hst[t] = 0;
    __syncthreads();
    int p = blk*256 + t;
    int bucket = (p >> 15)*16 + s2buf[p];
    atomicAdd(&hst[bucket], 1);
    __syncthreads();
    if (t < 32) bh[t*256 + blk] = hst[t];
}

// single block: walk table + totals -> wave-aligned starts -> offsets + padding
__global__ void k_prefix(const int* __restrict__ s2buf, const int* __restrict__ bh,
                         int* __restrict__ blockoff, int* __restrict__ wavebucket,
                         int* __restrict__ slotlist, int* __restrict__ walkrows) {
    __shared__ int tot[32], wst[32], offsh;
    __shared__ int T[16];
    int t = threadIdx.x;
    if (t < 16) T[t] = s2buf[t];
    if (t < 32) {
        int s = 0;
        for (int b = 0; b < 256; ++b) s += bh[t*256 + b];
        tot[t] = s;
    }
    __syncthreads();
    if (t < 16) {
        int w = t;
        walkrows[t*16 + 0] = w;
        for (int s = 1; s < 16; ++s) { w = T[w]; walkrows[t*16 + s] = w; }
    }
    if (t == 0) {
        int off = 0;
        for (int i = 0; i < 32; ++i) {
            wst[i] = off;
            off += ((tot[i] + 63) >> 6) << 6;
        }
        offsh = off;
    }
    __syncthreads();
    if (t < 32) {
        int run = wst[t];
        for (int b = 0; b < 256; ++b) {
            blockoff[t*256 + b] = run;
            run += bh[t*256 + b];
        }
        int w0 = wst[t] >> 6, nw = (tot[t] + 63) >> 6;
        for (int w = 0; w < nw; ++w) wavebucket[w0 + w] = t;
        for (int s = wst[t] + tot[t]; s < wst[t] + nw*64; ++s) slotlist[s] = -1;
    }
    __syncthreads();
    int off = offsh;
    for (int w = (off >> 6) + t; w < NWAVES; w += 256) wavebucket[w] = -1;
    for (int s = off + t; s < NSLOTS; s += 256) slotlist[s] = -1;
}

__global__ void k_scatter2(const int* __restrict__ s2buf,
                           const int* __restrict__ blockoff,
                           int* __restrict__ slotlist) {
    __shared__ int hst[32], base[32];
    int t = threadIdx.x, blk = blockIdx.x;
    if (t < 32) { hst[t] = 0; base[t] = blockoff[t*256 + blk]; }
    __syncthreads();
    int p = blk*256 + t;
    int bucket = (p >> 15)*16 + s2buf[p];
    int r = atomicAdd(&hst[bucket], 1);
    slotlist[base[bucket] + r] = p;
}

// ---------------------------------------------------------------------------
// 4) per (b, sv): window QKV -> f16 MFMA tables + softmax stats (+ weight cast)
//    window rows read from the f16 residual stream xh.
__global__ __launch_bounds__(256) void k_precomp(
        const half_t* __restrict__ xh,
        const float* __restrict__ Wq, const float* __restrict__ bq,
        const float* __restrict__ Wk, const float* __restrict__ bk,
        const float* __restrict__ Wv, const float* __restrict__ bv,
        const int* __restrict__ walkrows,
        half_t* __restrict__ Pq16, half_t* __restrict__ Pk16,
        half_t* __restrict__ PvT16, float* __restrict__ Pstat,
        half_t* __restrict__ wh) {
    int blk = blockIdx.x;
    int b = blk >> 4, sv = blk & 15;
    size_t bsv16 = (size_t)(b*16 + sv) * 1024;
    int bs48 = (b*16 + sv)*48;
    __shared__ float win[16][64];
    __shared__ float Wl[64][65];
    __shared__ float qw[16][65], kw[16][65];
    __shared__ float simw[16][17];
    __shared__ int wr[16];
    int t = threadIdx.x;
    #pragma unroll
    for (int j = 0; j < 2; ++j) {
        int idx = j*8192 + blk*256 + t;
        if (idx < 12288) {
            float v = idx < 4096 ? Wq[idx] : (idx < 8192 ? Wk[idx-4096] : Wv[idx-8192]);
            wh[idx] = (half_t)v;
        }
    }
    if (t < 16) wr[t] = walkrows[sv*16 + t];
    __syncthreads();
    #pragma unroll
    for (int i = 0; i < 4; ++i) {
        int idx = t + i*256; int tt = idx >> 6, c = idx & 63;
        win[tt][c] = (float)xh[((size_t)(b*NN + wr[tt]))*64 + c];
    }
    int wv = t >> 6, lane = t & 63;
    for (int m = 0; m < 3; ++m) {
        const float* W  = m == 0 ? Wq : (m == 1 ? Wk : Wv);
        const float* bb = m == 0 ? bq : (m == 1 ? bk : bv);
        __syncthreads();
        #pragma unroll
        for (int i = 0; i < 16; ++i) {
            int idx = t + i*256;
            Wl[idx >> 6][idx & 63] = W[idx];
        }
        __syncthreads();
        float acc[4] = {0.f, 0.f, 0.f, 0.f};
        for (int c = 0; c < 64; ++c) {
            float w_ = Wl[lane][c];
            #pragma unroll
            for (int r = 0; r < 4; ++r) acc[r] = fmaf(w_, win[wv*4 + r][c], acc[r]);
        }
        float bias = bb[lane];
        #pragma unroll
        for (int r = 0; r < 4; ++r) {
            int tt = wv*4 + r;
            float val = acc[r] + bias;
            if (m == 0)      { qw[tt][lane] = val; Pq16[bsv16 + tt*64 + lane] = (half_t)val; }
            else if (m == 1) { kw[tt][lane] = val; Pk16[bsv16 + tt*64 + lane] = (half_t)val; }
            else             {                     PvT16[bsv16 + lane*16 + tt] = (half_t)val; }
        }
    }
    __syncthreads();
    {
        int i = t >> 4, j = t & 15;
        float acc = 0.f;
        for (int o = 0; o < 64; ++o) acc = fmaf(qw[i][o], kw[j][o], acc);
        simw[i][j] = acc;
    }
    __syncthreads();
    if (t < 16) {
        float mx = simw[t][0];
        for (int j = 1; j < 16; ++j) mx = fmaxf(mx, simw[t][j]);
        float z = 0.f;
        for (int j = 0; j < 16; ++j) z += expf(simw[t][j] - mx);
        Pstat[bs48 + t*3 + 0] = mx;
        Pstat[bs48 + t*3 + 1] = z;
        Pstat[bs48 + t*3 + 2] = simw[t][t];
    }
}

// ---------------------------------------------------------------------------
// 5) QKV via f16 MFMA over SLOT-ordered points (input gathered via slotlist).
__global__ __launch_bounds__(256) void k_gemm(
        const half_t* __restrict__ xh, const int* __restrict__ slotlist, int s0,
        const half_t* __restrict__ wh,
        const float* __restrict__ bq, const float* __restrict__ bk,
        const float* __restrict__ bv,
        half_t* __restrict__ qh, half_t* __restrict__ kh, half_t* __restrict__ vh) {
    __shared__ __align__(16) half_t XO[256*72];
    __shared__ __align__(16) half_t WL[192*72];
    int t = threadIdx.x;
    int lane = t & 63, wv = t >> 6;
    size_t go = (size_t)blockIdx.x * 256 * 64;
    {
        int srow = slotlist[s0 + blockIdx.x*256 + t];
        int prow = srow < 0 ? 0 : srow;
        const uint4* src = (const uint4*)(xh + (size_t)prow*64);
        #pragma unroll
        for (int j = 0; j < 8; ++j) *(uint4*)&XO[t*72 + j*8] = src[j];
    }
    #pragma unroll
    for (int j = 0; j < 6; ++j) {
        int idx8 = t + j*256;
        int row = idx8 >> 3, c0 = (idx8 & 7) * 8;
        *(uint4*)&WL[row*72 + c0] = *(const uint4*)(wh + idx8*8);
    }
    __syncthreads();
    int m15 = lane & 15, k0 = (lane >> 4) * 8;
    int ar = wv*64 + m15;
    f16x8 a00 = *(const f16x8*)&XO[(ar    )*72 + k0];
    f16x8 a01 = *(const f16x8*)&XO[(ar    )*72 + k0 + 32];
    f16x8 a10 = *(const f16x8*)&XO[(ar+16)*72 + k0];
    f16x8 a11 = *(const f16x8*)&XO[(ar+16)*72 + k0 + 32];
    f16x8 a20 = *(const f16x8*)&XO[(ar+32)*72 + k0];
    f16x8 a21 = *(const f16x8*)&XO[(ar+32)*72 + k0 + 32];
    f16x8 a30 = *(const f16x8*)&XO[(ar+48)*72 + k0];
    f16x8 a31 = *(const f16x8*)&XO[(ar+48)*72 + k0 + 32];
    __syncthreads();
    #pragma unroll 1
    for (int m = 0; m < 3; ++m) {
        const float* bias = m == 0 ? bq : (m == 1 ? bk : bv);
        half_t* outp      = m == 0 ? qh : (m == 1 ? kh : vh);
        int wb = m*64 + m15;
        f16x8 b00 = *(const f16x8*)&WL[(wb    )*72 + k0];
        f16x8 b01 = *(const f16x8*)&WL[(wb    )*72 + k0 + 32];
        f16x8 b10 = *(const f16x8*)&WL[(wb+16)*72 + k0];
        f16x8 b11 = *(const f16x8*)&WL[(wb+16)*72 + k0 + 32];
        f16x8 b20 = *(const f16x8*)&WL[(wb+32)*72 + k0];
        f16x8 b21 = *(const f16x8*)&WL[(wb+32)*72 + k0 + 32];
        f16x8 b30 = *(const f16x8*)&WL[(wb+48)*72 + k0];
        f16x8 b31 = *(const f16x8*)&WL[(wb+48)*72 + k0 + 32];
        float bs0 = bias[m15], bs1 = bias[16+m15], bs2 = bias[32+m15], bs3 = bias[48+m15];
        f32x4 Z = {0.f, 0.f, 0.f, 0.f};
        f32x4 c00=Z,c01=Z,c02=Z,c03=Z, c10=Z,c11=Z,c12=Z,c13=Z;
        f32x4 c20=Z,c21=Z,c22=Z,c23=Z, c30=Z,c31=Z,c32=Z,c33=Z;
        #define MM(i,j) \
            c##i##j = __builtin_amdgcn_mfma_f32_16x16x32_f16(a##i##0, b##j##0, c##i##j, 0,0,0); \
            c##i##j = __builtin_amdgcn_mfma_f32_16x16x32_f16(a##i##1, b##j##1, c##i##j, 0,0,0);
        MM(0,0) MM(0,1) MM(0,2) MM(0,3)
        MM(1,0) MM(1,1) MM(1,2) MM(1,3)
        MM(2,0) MM(2,1) MM(2,2) MM(2,3)
        MM(3,0) MM(3,1) MM(3,2) MM(3,3)
        #undef MM
        __syncthreads();
        int r0 = wv*64 + ((lane >> 4) << 2);
        #define WR(i,j,bsj) { \
            XO[(r0 + i*16 + 0)*64 + j*16 + m15] = (half_t)(c##i##j[0] + bsj); \
            XO[(r0 + i*16 + 1)*64 + j*16 + m15] = (half_t)(c##i##j[1] + bsj); \
            XO[(r0 + i*16 + 2)*64 + j*16 + m15] = (half_t)(c##i##j[2] + bsj); \
            XO[(r0 + i*16 + 3)*64 + j*16 + m15] = (half_t)(c##i##j[3] + bsj); }
        WR(0,0,bs0) WR(0,1,bs1) WR(0,2,bs2) WR(0,3,bs3)
        WR(1,0,bs0) WR(1,1,bs1) WR(1,2,bs2) WR(1,3,bs3)
        WR(2,0,bs0) WR(2,1,bs1) WR(2,2,bs2) WR(2,3,bs3)
        WR(3,0,bs0) WR(3,1,bs1) WR(3,2,bs2) WR(3,3,bs3)
        #undef WR
        __syncthreads();
        #pragma unroll
        for (int j = 0; j < 8; ++j) {
            int idx = (j*256 + t) * 8;
            *(uint4*)(outp + go + idx) = *(const uint4*)&XO[idx];
        }
    }
}

// ---------------------------------------------------------------------------
// 6) combine v4: MFMA attention, one wave = 16 slots (j-tile = wave id).
__global__ __launch_bounds__(256) void k_comb4(
        const half_t* __restrict__ qh, const half_t* __restrict__ kh,
        const half_t* __restrict__ vh,
        const half_t* __restrict__ Pq16, const half_t* __restrict__ Pk16,
        const half_t* __restrict__ PvT16, const float* __restrict__ Pstat,
        const int* __restrict__ slotlist, const int* __restrict__ wavebucket,
        half_t* __restrict__ xo, int s0) {
    int t = threadIdx.x, j = t >> 6, lane = t & 63;
    int wslot = blockIdx.x*64;
    int gbase = s0 + wslot;
    int bucket = wavebucket[gbase >> 6];
    if (bucket < 0) return;
    int m15 = lane & 15, g4 = lane >> 4;
    int k0h = g4 * 8;
    size_t bsv16 = (size_t)bucket << 10;
    int bs48 = bucket * 48;

    f16x8 pqA0 = *(const f16x8*)&Pq16[bsv16 + m15*64 + k0h];
    f16x8 pqA1 = *(const f16x8*)&Pq16[bsv16 + m15*64 + k0h + 32];
    f16x8 pkA0 = *(const f16x8*)&Pk16[bsv16 + m15*64 + k0h];
    f16x8 pkA1 = *(const f16x8*)&Pk16[bsv16 + m15*64 + k0h + 32];
    f16x4 pvB0 = *(const f16x4*)&PvT16[bsv16 + (0*16 + m15)*16 + g4*4];
    f16x4 pvB1 = *(const f16x4*)&PvT16[bsv16 + (1*16 + m15)*16 + g4*4];
    f16x4 pvB2 = *(const f16x4*)&PvT16[bsv16 + (2*16 + m15)*16 + g4*4];
    f16x4 pvB3 = *(const f16x4*)&PvT16[bsv16 + (3*16 + m15)*16 + g4*4];
    float pm[4], pz[4], dg[4];
    #pragma unroll
    for (int r = 0; r < 4; ++r) {
        pm[r] = Pstat[bs48 + (g4*4+r)*3 + 0];
        pz[r] = Pstat[bs48 + (g4*4+r)*3 + 1];
        dg[r] = Pstat[bs48 + (g4*4+r)*3 + 2];
    }
    int4 pid4 = *(const int4*)&slotlist[gbase + j*16 + g4*4];

    const half_t* kp = kh + (size_t)(wslot + j*16 + m15)*64;
    const half_t* qp = qh + (size_t)(wslot + j*16 + m15)*64;
    f16x8 kB0 = *(const f16x8*)&kp[k0h];
    f16x8 kB1 = *(const f16x8*)&kp[k0h + 32];
    f16x8 qB0 = *(const f16x8*)&qp[k0h];
    f16x8 qB1 = *(const f16x8*)&qp[k0h + 32];
    f32x4 Zz = {0.f,0.f,0.f,0.f};
    f32x4 sp = __builtin_amdgcn_mfma_f32_16x16x32_f16(pqA0, kB0, Zz, 0,0,0);
    sp = __builtin_amdgcn_mfma_f32_16x16x32_f16(pqA1, kB1, sp, 0,0,0);
    f32x4 tp = __builtin_amdgcn_mfma_f32_16x16x32_f16(pkA0, qB0, Zz, 0,0,0);
    tp = __builtin_amdgcn_mfma_f32_16x16x32_f16(pkA1, qB1, tp, 0,0,0);
    float up = 0.f;
    #pragma unroll
    for (int e = 0; e < 8; ++e) {
        up = fmaf((float)qB0[e], (float)kB0[e], up);
        up = fmaf((float)qB1[e], (float)kB1[e], up);
    }
    up += __shfl_xor(up, 16, 64);
    up += __shfl_xor(up, 32, 64);
    float d0, d1, d2, d3;
    {
        float mi, zi;
        mi = fmaxf(pm[0], sp[0]); zi = pz[0]*expf(pm[0]-mi) + expf(sp[0]-mi); d0 = expf(dg[0]-mi)/zi;
        mi = fmaxf(pm[1], sp[1]); zi = pz[1]*expf(pm[1]-mi) + expf(sp[1]-mi); d1 = expf(dg[1]-mi)/zi;
        mi = fmaxf(pm[2], sp[2]); zi = pz[2]*expf(pm[2]-mi) + expf(sp[2]-mi); d2 = expf(dg[2]-mi)/zi;
        mi = fmaxf(pm[3], sp[3]); zi = pz[3]*expf(pm[3]-mi) + expf(sp[3]-mi); d3 = expf(dg[3]-mi)/zi;
    }
    float tmax = fmaxf(fmaxf(tp[0], tp[1]), fmaxf(tp[2], tp[3]));
    tmax = fmaxf(tmax, __shfl_xor(tmax, 16, 64));
    tmax = fmaxf(tmax, __shfl_xor(tmax, 32, 64));
    float mc = fmaxf(tmax, up);
    float ze = expf(tp[0]-mc) + expf(tp[1]-mc) + expf(tp[2]-mc) + expf(tp[3]-mc);
    ze += __shfl_xor(ze, 16, 64);
    ze += __shfl_xor(ze, 32, 64);
    float ec = expf(up - mc);
    float dcen = ec / (ze + ec);
    f16x4 dA; dA[0] = (half_t)d0; dA[1] = (half_t)d1; dA[2] = (half_t)d2; dA[3] = (half_t)d3;

    float dc0 = __shfl(dcen, g4*4 + 0, 64);
    float dc1 = __shfl(dcen, g4*4 + 1, 64);
    float dc2 = __shfl(dcen, g4*4 + 2, 64);
    float dc3 = __shfl(dcen, g4*4 + 3, 64);
    int p0 = pid4.x, p1 = pid4.y, p2 = pid4.z, p3 = pid4.w;
    size_t vb0 = (size_t)(wslot + j*16 + g4*4 + 0)*64;
    size_t vb1 = (size_t)(wslot + j*16 + g4*4 + 1)*64;
    size_t vb2 = (size_t)(wslot + j*16 + g4*4 + 2)*64;
    size_t vb3 = (size_t)(wslot + j*16 + g4*4 + 3)*64;
    #pragma unroll
    for (int jc = 0; jc < 4; ++jc) {
        f16x4 pvB = jc == 0 ? pvB0 : (jc == 1 ? pvB1 : (jc == 2 ? pvB2 : pvB3));
        f32x4 Z2 = {0.f,0.f,0.f,0.f};
        f32x4 acc = __builtin_amdgcn_mfma_f32_16x16x16f16(dA, pvB, Z2, 0,0,0);
        int c = jc*16 + m15;
        float v0 = (float)vh[vb0 + c];
        float v1 = (float)vh[vb1 + c];
        float v2 = (float)vh[vb2 + c];
        float v3 = (float)vh[vb3 + c];
        if (p0 >= 0) xo[(size_t)p0*64 + c] = (half_t)(acc[0] + dc0*v0);
        if (p1 >= 0) xo[(size_t)p1*64 + c] = (half_t)(acc[1] + dc1*v1);
        if (p2 >= 0) xo[(size_t)p2*64 + c] = (half_t)(acc[2] + dc2*v2);
        if (p3 >= 0) xo[(size_t)p3*64 + c] = (half_t)(acc[3] + dc3*v3);
    }
}

// ---------------------------------------------------------------------------
// 7) partial sums (512 blocks x 4 waves, deterministic), f16 input
__global__ __launch_bounds__(256) void k_reduce(const half_t* __restrict__ x,
                                                float* __restrict__ part) {
    __shared__ float ls[4][64], lq[4][64];
    int t = threadIdx.x, q = t >> 6, c = t & 63;
    size_t base = ((size_t)blockIdx.x*128 + q*32) * 64;
    float s = 0.f, sq = 0.f;
    for (int r = 0; r < 32; ++r) {
        float v = (float)x[base + r*64 + c];
        s += v; sq = fmaf(v, v, sq);
    }
    ls[q][c] = s; lq[q][c] = sq;
    __syncthreads();
    if (q == 0) {
        float S = ls[0][c] + ls[1][c] + ls[2][c] + ls[3][c];
        float Q = lq[0][c] + lq[1][c] + lq[2][c] + lq[3][c];
        part[blockIdx.x*64 + c] = S;
        part[512*64 + blockIdx.x*64 + c] = Q;
    }
}

// 8) finalize mean/var per channel
__global__ __launch_bounds__(256) void k_stats(const float* __restrict__ part,
                                               float* __restrict__ mv) {
    __shared__ float ls[4][64], lq[4][64];
    int t = threadIdx.x, q = t >> 6, c = t & 63;
    float s = 0.f, sq = 0.f;
    for (int r = q*128; r < q*128 + 128; ++r) {
        s  += part[r*64 + c];
        sq += part[512*64 + r*64 + c];
    }
    ls[q][c] = s; lq[q][c] = sq;
    __syncthreads();
    if (q == 0) {
        float S = ls[0][c] + ls[1][c] + ls[2][c] + ls[3][c];
        float Q = lq[0][c] + lq[1][c] + lq[2][c] + lq[3][c];
        float mean = S / (float)NPTS;
        float var  = Q / (float)NPTS - mean*mean;
        mv[c] = mean; mv[64 + c] = var;
    }
}

// ---------------------------------------------------------------------------
// 9) normalize + relu + residual on the f16 stream; write out slice (B,C,N)
__global__ void k_norm(const half_t* __restrict__ x, half_t* __restrict__ xh,
                       const float* __restrict__ mv,
                       const float* __restrict__ gamma, const float* __restrict__ beta,
                       float* __restrict__ out, int l) {
    int blk = blockIdx.x;
    int b = blk / (NN/64);
    int n0 = (blk % (NN/64)) * 64;
    __shared__ float tile[64][65];
    int t = threadIdx.x;
    int c = t & 63, d0 = t >> 6;
    float mean = mv[c], var = mv[64+c];
    float inv = 1.0f / sqrtf(var + 1e-5f);
    float ga = gamma[c], be = beta[c];
    for (int i = 0; i < 16; ++i) {
        int dn = d0 + i*4;
        size_t pi = ((size_t)(b*NN + n0 + dn))*64 + c;
        float xv = (float)x[pi];
        float res = (float)xh[pi];
        float y = res + fmaxf(ga * (xv - mean) * inv + be, 0.f);
        xh[pi] = (half_t)y;
        tile[dn][c] = y;
    }
    __syncthreads();
    int dn2 = t & 63, c0 = t >> 6;
    for (int i = 0; i < 16; ++i) {
        int cc = c0 + i*4;
        out[((size_t)(b*192 + l*64 + cc))*NN + n0 + dn2] = tile[dn2][cc];
    }
}

// ---------------------------------------------------------------------------
extern "C" void kernel_launch(void* const* d_in, const int* in_sizes, int n_in,
                              void* d_out, int out_size, void* d_ws, size_t ws_size,
                              hipStream_t stream) {
    const float* feature = (const float*)d_in[0];
    const int*   knn     = (const int*)d_in[1];
    const float* Wq = (const float*)d_in[2];
    const float* bq = (const float*)d_in[3];
    const float* Wk = (const float*)d_in[4];
    const float* bk = (const float*)d_in[5];
    const float* Wv = (const float*)d_in[6];
    const float* bv = (const float*)d_in[7];
    const float* gamma = (const float*)d_in[8];
    const float* beta  = (const float*)d_in[9];
    float* out = (float*)d_out;

    char* ws = (char*)d_ws;
    float*  fT    = (float*) ws;                        // 16,777,216
    half_t* xh    = (half_t*)(ws + 16777216);           //  8,388,608
    half_t* xo    = (half_t*)(ws + 25165824);           //  8,388,608
    int*    s2buf = (int*)   (ws + 33554432);           //    262,144
    int*    walkrows = (int*)(ws + 33816576);           //      1,024
    half_t* Pq16  = (half_t*)(ws + 33817600);           //     65,536
    half_t* Pk16  = (half_t*)(ws + 33883136);           //     65,536
    half_t* PvT16 = (half_t*)(ws + 33948672);           //     65,536
    float*  Pstat = (float*) (ws + 34014208);           //      6,144
    float*  part  = (float*) (ws + 34020352);           //    262,144
    float*  mv    = (float*) (ws + 34282496);           //        512
    half_t* wh    = (half_t*)(ws + 34283008);           //     24,576
    int*    bh        = (int*)(ws + 34307584);          //     32,768
    int*    blockoff  = (int*)(ws + 34340352);          //     32,768
    int*    wavebucket= (int*)(ws + 34373120);          //      4,224
    int*    slotlist  = (int*)(ws + 34377344);          //    270,336
    size_t  qkv_off = 34647680;

    size_t avail = ws_size > qkv_off ? ws_size - qkv_off : 0;
    size_t chunk = avail / 384;      // 3 x 64 x 2B per slot
    chunk = (chunk / 256) * 256;
    if (chunk > (size_t)NSLOTS) chunk = NSLOTS;
    if (chunk < 256) chunk = 256;
    half_t* qh = (half_t*)(ws + qkv_off);
    half_t* kh = qh + chunk*64;
    half_t* vh = kh + chunk*64;

    k_transpose<<<NB*(NN/64), 256, 0, stream>>>(feature, fT, xh);
    k_s2<<<NPTS/16, 256, 0, stream>>>(fT, knn, s2buf);
    k_hist2<<<NPTS/256, 256, 0, stream>>>(s2buf, bh);
    k_prefix<<<1, 256, 0, stream>>>(s2buf, bh, blockoff, wavebucket, slotlist,
                                    walkrows);
    k_scatter2<<<NPTS/256, 256, 0, stream>>>(s2buf, blockoff, slotlist);

    for (int l = 0; l < 3; ++l) {
        k_precomp<<<32, 256, 0, stream>>>(xh, Wq + l*4096, bq + l*64,
                                          Wk + l*4096, bk + l*64,
                                          Wv + l*4096, bv + l*64,
                                          walkrows, Pq16, Pk16, PvT16, Pstat, wh);
        for (size_t s0 = 0; s0 < NSLOTS; s0 += chunk) {
            size_t cn = (s0 + chunk <= NSLOTS) ? chunk : (NSLOTS - s0);
            k_gemm<<<(unsigned)(cn/256), 256, 0, stream>>>(xh, slotlist, (int)s0, wh,
                                                           bq + l*64, bk + l*64, bv + l*64,
                                                           qh, kh, vh);
            k_comb4<<<(unsigned)(cn/64), 256, 0, stream>>>(qh, kh, vh,
                                                           Pq16, Pk16, PvT16, Pstat,
                                                           slotlist, wavebucket,
                                                           xo, (int)s0);
        }
        k_reduce<<<512, 256, 0, stream>>>(xo, part);
        k_stats<<<1, 256, 0, stream>>>(part, mv);
        k_norm<<<NB*(NN/64), 256, 0, stream>>>(xo, xh, mv, gamma + l*64, beta + l*64,
                                               out, l);
    }
}